// Round 9
// baseline (136.695 us; speedup 1.0000x reference)
//
#include <hip/hip_runtime.h>

#define D 128
#define BN 64            // nodes per block (4 waves x 16)
#define WN 16            // nodes per wave
#define ECAP 2048        // edge cap per block (mean 1024, 32 sigma headroom)
#define CH 32            // edges per chunk
typedef unsigned int uint32;
typedef __bf16 bf16x8 __attribute__((ext_vector_type(8)));
typedef float f32x4 __attribute__((ext_vector_type(4)));
typedef int intx2 __attribute__((ext_vector_type(2)));
typedef __attribute__((address_space(1))) const void* gas_ptr;
typedef __attribute__((address_space(3))) void* las_ptr;

__device__ __forceinline__ unsigned short f2bf(float f) {
    unsigned u = __float_as_uint(f);
    unsigned r = u + 0x7FFFu + ((u >> 16) & 1u);   // round-to-nearest-even
    return (unsigned short)(r >> 16);
}
__device__ __forceinline__ float bflo(uint32 u) { return __uint_as_float(u << 16); }
__device__ __forceinline__ float bfhi(uint32 u) { return __uint_as_float(u & 0xFFFF0000u); }

__device__ __forceinline__ void fma8(float* acc, uint4 r, float v) {
    acc[0] += v * bflo(r.x); acc[1] += v * bfhi(r.x);
    acc[2] += v * bflo(r.y); acc[3] += v * bfhi(r.y);
    acc[4] += v * bflo(r.z); acc[5] += v * bfhi(r.z);
    acc[6] += v * bflo(r.w); acc[7] += v * bfhi(r.w);
}

// ---------------------------------------------------------------------------
// Fused prep: x->bf16 | CSR row_ptr | W transpose+convert
// ---------------------------------------------------------------------------
__global__ __launch_bounds__(256) void prep_kernel(
    const float* __restrict__ x, unsigned short* __restrict__ xh, int n8,
    const int* __restrict__ row, int* __restrict__ row_ptr,
    int n_nodes, int n_edges,
    const float* __restrict__ Wl, const float* __restrict__ Wr,
    unsigned short* __restrict__ Wlt, unsigned short* __restrict__ Wrt,
    int nbConv, int nbRp) {
    const int b = blockIdx.x;
    if (b < nbConv) {
        const int id = b * 256 + threadIdx.x;
        if (id < n8) {
            const float4* p = (const float4*)x + (size_t)id * 2;
            float4 a = p[0], bb = p[1];
            uint4 o;
            o.x = f2bf(a.x) | ((uint32)f2bf(a.y) << 16);
            o.y = f2bf(a.z) | ((uint32)f2bf(a.w) << 16);
            o.z = f2bf(bb.x) | ((uint32)f2bf(bb.y) << 16);
            o.w = f2bf(bb.z) | ((uint32)f2bf(bb.w) << 16);
            ((uint4*)xh)[id] = o;
        }
    } else if (b < nbConv + nbRp) {
        const int e = (b - nbConv) * 256 + threadIdx.x;
        if (e < n_edges) {
            const int r = row[e];
            const int rp = (e == 0) ? -1 : row[e - 1];
            for (int n = rp + 1; n <= r; ++n) row_ptr[n] = e;
            if (e == n_edges - 1)
                for (int n = r + 1; n <= n_nodes; ++n) row_ptr[n] = n_edges;
        }
    } else {
        const int id = (b - nbConv - nbRp) * 256 + threadIdx.x;   // 0..16383
        if (id < 16384) {
            const int n = id & 127, k = id >> 7;
            Wlt[n * 128 + k] = f2bf(Wl[k * 128 + n]);
            Wrt[n * 128 + k] = f2bf(Wr[k * 128 + n]);
        }
    }
}

// ---------------------------------------------------------------------------
// MFMA SpMM: for each 16-node wave-tile, out_l[16x128] = sum over 32-edge
// chunks of P[16x32] @ Xg[32x128], P = val-scatter (P[r][k]=val_k iff
// row_k==r). Edges need no per-node alignment: P masks neighbors' edges in
// shared boundary chunks and tail garbage.
// Staging: global_load_lds, per-lane source arranged so linear LDS becomes
// [nt=8][ktperm=8][4 edges][16 feats] (ktperm = 0,2,4,6,1,3,5,7). B-frags
// via ds_read_b64_tr_b16 (addr = ntbase + lane*8; second read offset:512).
// Double-buffered, vmcnt(8)-gated. A-frag (P) built in-register from packed
// (row_local | valbf16<<16) LDS words.
// ---------------------------------------------------------------------------
__global__ __launch_bounds__(256) void spmm_mfma_kernel(
    const unsigned short* __restrict__ xh,
    const int* __restrict__ row_ptr,
    const int* __restrict__ row,
    const int* __restrict__ col,
    const float* __restrict__ val,
    unsigned short* __restrict__ outlh, int n_nodes) {
    __shared__ int    scol[ECAP];        // 8 KB
    __shared__ uint32 srv[ECAP];         // 8 KB: (row-nb0) | valbf16<<16
    __shared__ char   gbuf[4][2][8192];  // 64 KB: [wave][buf][nt][ktperm][4][16]
    const int tid = threadIdx.x;
    const int nb0 = blockIdx.x * BN;
    const int E0 = row_ptr[nb0];
    const int E1 = row_ptr[min(nb0 + BN, n_nodes)];
    const int ne = E1 - E0;
    const bool fits = (ne <= ECAP - CH);
    if (fits) {
        for (int t = tid; t < ECAP; t += 256) {
            if (t < ne) {
                scol[t] = col[E0 + t];
                srv[t] = (uint32)(row[E0 + t] - nb0) |
                         ((uint32)f2bf(val[E0 + t]) << 16);
            } else { scol[t] = 0; srv[t] = 0xFFFFu; }
        }
    }
    __syncthreads();

    const int wv = tid >> 6, lane = tid & 63;
    const int n0 = nb0 + wv * WN;

    int s = 0, e = 0;
    if (n0 < n_nodes) { s = row_ptr[n0]; e = row_ptr[min(n0 + WN, n_nodes)]; }

    if (fits) {
        int c0 = 0, nch = 0;
        if (e > s) {
            c0 = (s - E0) >> 5;
            nch = ((e - E0 + CH - 1) >> 5) - c0;
        }

        const int rbase = wv * WN + (lane & 15);  // my A-row's block-local node
        const int half = lane >> 4;               // 0..3
        char* wbuf = &gbuf[wv][0][0];
        const char* xb = (const char*)xh;

        // staging lane decomposition (constant per thread)
        const int f_ = lane >> 3, sidx = lane & 7;
        const int kt_ = (f_ < 4) ? 2 * f_ : 2 * f_ - 7;   // ktperm inverse
        const int j_ = sidx >> 1, hh = sidx & 1;

        f32x4 acc[8];
#pragma unroll
        for (int nt = 0; nt < 8; ++nt) acc[nt] = (f32x4){0.f, 0.f, 0.f, 0.f};

        // stage chunk ch (block grid) into buffer b
        auto stage = [&](int ch, int b) {
            const int er = ch * CH + kt_ * 4 + j_;       // < ECAP by fits guard
            const int c = scol[er];                      // per-lane LDS gather
            const char* src = xb + (size_t)(unsigned)c * 256u + hh * 16;
            char* dst = wbuf + b * 8192;
#pragma unroll
            for (int nt = 0; nt < 8; ++nt) {
                __builtin_amdgcn_global_load_lds(
                    (gas_ptr)(src + nt * 32), (las_ptr)(dst + nt * 1024),
                    16, 0, 0);
            }
        };

        if (nch > 0) stage(c0, 0);

        for (int t = 0; t < nch; ++t) {
            const int b = t & 1;
            if (t + 1 < nch) {
                stage(c0 + t + 1, b ^ 1);
                __builtin_amdgcn_s_waitcnt(0x0F78);   // vmcnt(8): buf b landed
            } else {
                __builtin_amdgcn_s_waitcnt(0x0F70);   // vmcnt(0)
            }
            __builtin_amdgcn_sched_barrier(0);

            // ---- A fragment (P) from srv ----
            const uint32* pp = &srv[(c0 + t) * CH + half * 8];
            const uint4 w0 = *(const uint4*)pp;
            const uint4 w1 = *(const uint4*)(pp + 4);
            uint4 af;
            {
                uint32 lo, hi;
                lo = ((w0.x & 0xFFFFu) == (uint32)rbase) ? (w0.x >> 16) : 0u;
                hi = ((w0.y & 0xFFFFu) == (uint32)rbase) ? (w0.y & 0xFFFF0000u) : 0u;
                af.x = lo | hi;
                lo = ((w0.z & 0xFFFFu) == (uint32)rbase) ? (w0.z >> 16) : 0u;
                hi = ((w0.w & 0xFFFFu) == (uint32)rbase) ? (w0.w & 0xFFFF0000u) : 0u;
                af.y = lo | hi;
                lo = ((w1.x & 0xFFFFu) == (uint32)rbase) ? (w1.x >> 16) : 0u;
                hi = ((w1.y & 0xFFFFu) == (uint32)rbase) ? (w1.y & 0xFFFF0000u) : 0u;
                af.z = lo | hi;
                lo = ((w1.z & 0xFFFFu) == (uint32)rbase) ? (w1.z >> 16) : 0u;
                hi = ((w1.w & 0xFFFFu) == (uint32)rbase) ? (w1.w & 0xFFFF0000u) : 0u;
                af.w = lo | hi;
            }
            const bf16x8 a = __builtin_bit_cast(bf16x8, af);

            // ---- B fragments via hardware transpose reads ----
            const unsigned lb0 =
                (unsigned)(size_t)(las_ptr)(wbuf + b * 8192) + (unsigned)lane * 8u;
            intx2 t0[8], t1[8];
#pragma unroll
            for (int nt = 0; nt < 8; ++nt) {
                const unsigned ab = lb0 + (unsigned)nt * 1024u;
                asm volatile("ds_read_b64_tr_b16 %0, %1"
                             : "=v"(t0[nt]) : "v"(ab));
                asm volatile("ds_read_b64_tr_b16 %0, %1 offset:512"
                             : "=v"(t1[nt]) : "v"(ab));
            }
            __builtin_amdgcn_s_waitcnt(0xC07F);       // lgkmcnt(0)
            __builtin_amdgcn_sched_barrier(0);
#pragma unroll
            for (int nt = 0; nt < 8; ++nt) {
                uint4 bw;
                bw.x = (uint32)t0[nt].x; bw.y = (uint32)t0[nt].y;
                bw.z = (uint32)t1[nt].x; bw.w = (uint32)t1[nt].y;
                const bf16x8 bf = __builtin_bit_cast(bf16x8, bw);
                acc[nt] = __builtin_amdgcn_mfma_f32_16x16x32_bf16(
                    a, bf, acc[nt], 0, 0, 0);
            }
        }

        // ---- epilogue: C row = half*4+j, col = nt*16 + (lane&15) ----
#pragma unroll
        for (int nt = 0; nt < 8; ++nt) {
#pragma unroll
            for (int j = 0; j < 4; ++j) {
                const int n = n0 + half * 4 + j;
                if (n < n_nodes)
                    outlh[(size_t)n * D + nt * 16 + (lane & 15)] =
                        f2bf(acc[nt][j]);
            }
        }
    } else {
        // rare fallback: block's edge range exceeds LDS cap. 16-lane group
        // per node, scalar gather loop.
        const int g = lane >> 4, lq = lane & 15;
        const int n = n0 + ((lane >> 4) + 0); // placeholder to keep shape
        // group-per-node over the wave's 16 nodes, 4 groups -> 4 passes
        for (int pass = 0; pass < 4; ++pass) {
            const int node = n0 + pass * 4 + g;
            if (node >= n_nodes) continue;
            const int ss = row_ptr[node];
            const int ee = row_ptr[node + 1];
            float acc[8] = {0.f,0.f,0.f,0.f,0.f,0.f,0.f,0.f};
            for (int jj = ss; jj < ee; ++jj) {
                const int c = col[jj];
                const float v = val[jj];
                const uint4 r = *(const uint4*)&xh[(size_t)c * D + lq * 8];
                fma8(acc, r, v);
            }
            uint4 o;
            o.x = f2bf(acc[0]) | ((uint32)f2bf(acc[1]) << 16);
            o.y = f2bf(acc[2]) | ((uint32)f2bf(acc[3]) << 16);
            o.z = f2bf(acc[4]) | ((uint32)f2bf(acc[5]) << 16);
            o.w = f2bf(acc[6]) | ((uint32)f2bf(acc[7]) << 16);
            *(uint4*)&outlh[(size_t)node * D + lq * 8] = o;
        }
    }
}

// ---------------------------------------------------------------------------
// MFMA GEMM: out = [out_l_h | xh] @ [Wlt;Wrt]^T + b_l  (K=256 bf16 -> f32)
// ---------------------------------------------------------------------------
__global__ __launch_bounds__(256) void gemm_mfma_kernel(
    const unsigned short* __restrict__ xh,
    const unsigned short* __restrict__ outlh,
    const unsigned short* __restrict__ Wlt,
    const unsigned short* __restrict__ Wrt,
    const float* __restrict__ b_l,
    float* __restrict__ out, int M) {
    const int tid = threadIdx.x;
    const int wid = tid >> 6, lane = tid & 63;
    const int wm = wid >> 1, wn = wid & 1;
    const int m0 = blockIdx.x * 64 + wm * 32;
    const int n0 = wn * 64;
    const int fr = lane & 15;
    const int kofs = (lane >> 4) * 8;

    f32x4 acc[2][4];
#pragma unroll
    for (int mr = 0; mr < 2; ++mr)
#pragma unroll
        for (int nr = 0; nr < 4; ++nr) acc[mr][nr] = (f32x4){0.f, 0.f, 0.f, 0.f};

#pragma unroll
    for (int s = 0; s < 8; ++s) {
        const unsigned short* Abase = (s < 4) ? outlh : xh;
        const unsigned short* Wbase = (s < 4) ? Wlt : Wrt;
        const int k0 = (s & 3) * 32;
        bf16x8 a[2], b[4];
#pragma unroll
        for (int mr = 0; mr < 2; ++mr)
            a[mr] = *(const bf16x8*)&Abase[(m0 + mr * 16 + fr) * D + k0 + kofs];
#pragma unroll
        for (int nr = 0; nr < 4; ++nr)
            b[nr] = *(const bf16x8*)&Wbase[(n0 + nr * 16 + fr) * D + k0 + kofs];
#pragma unroll
        for (int mr = 0; mr < 2; ++mr)
#pragma unroll
            for (int nr = 0; nr < 4; ++nr)
                acc[mr][nr] = __builtin_amdgcn_mfma_f32_16x16x32_bf16(
                    a[mr], b[nr], acc[mr][nr], 0, 0, 0);
    }

    const int r0 = (lane >> 4) * 4;
#pragma unroll
    for (int nr = 0; nr < 4; ++nr) {
        const int ncol = n0 + nr * 16 + fr;
        const float bias = b_l[ncol];
#pragma unroll
        for (int mr = 0; mr < 2; ++mr) {
#pragma unroll
            for (int j = 0; j < 4; ++j) {
                const int m = m0 + mr * 16 + r0 + j;
                if (m < M) out[m * D + ncol] = acc[mr][nr][j] + bias;
            }
        }
    }
}

// ===========================================================================
// Fallback f32 path if ws is too small for bf16 staging.
// ===========================================================================
__global__ void build_rowptr_kernel(const int* __restrict__ row,
                                    int* __restrict__ row_ptr,
                                    int n_nodes, int n_edges) {
    int e = blockIdx.x * blockDim.x + threadIdx.x;
    if (e >= n_edges) return;
    int r = row[e];
    int rp = (e == 0) ? -1 : row[e - 1];
    for (int n = rp + 1; n <= r; ++n) row_ptr[n] = e;
    if (e == n_edges - 1)
        for (int n = r + 1; n <= n_nodes; ++n) row_ptr[n] = n_edges;
}

__global__ __launch_bounds__(128) void spmm_kernel(
    const float* __restrict__ x, const int* __restrict__ row_ptr,
    const int* __restrict__ col, const float* __restrict__ val,
    float* __restrict__ out_l) {
    const int n = blockIdx.x;
    const int d = threadIdx.x;
    const int start = row_ptr[n];
    const int end = row_ptr[n + 1];
    float acc = 0.0f;
    for (int e = start; e < end; ++e)
        acc += val[e] * x[(size_t)col[e] * D + d];
    out_l[(size_t)n * D + d] = acc;
}

__global__ __launch_bounds__(256) void fused_gemm_kernel(
    const float* __restrict__ xin, const float* __restrict__ W_l,
    const float* __restrict__ b_l, const float* __restrict__ W_r,
    float* __restrict__ out, int M) {
    __shared__ float As[64][68];
    __shared__ float Ws[64][132];
    const int tid = threadIdx.x;
    const int tx = tid & 15;
    const int ty = tid >> 4;
    const int ty4 = ty * 4;
    const int m0 = blockIdx.x * 64;
    float acc[4][8];
#pragma unroll
    for (int i = 0; i < 4; ++i)
#pragma unroll
        for (int j = 0; j < 8; ++j) acc[i][j] = 0.0f;
    for (int kt = 0; kt < 4; ++kt) {
        const float* Asrc = (kt < 2) ? out : xin;
        const float* Wsrc = (kt < 2) ? W_l : W_r;
        const int koff = (kt & 1) * 64;
        __syncthreads();
#pragma unroll
        for (int r = 0; r < 4; ++r) {
            const int idx = tid + r * 256;
            const int m = idx >> 4;
            const int kq = idx & 15;
            float4 a = make_float4(0.f, 0.f, 0.f, 0.f);
            if (m0 + m < M)
                a = *(const float4*)&Asrc[(size_t)(m0 + m) * D + koff + kq * 4];
            *(float4*)&As[m][kq * 4] = a;
        }
#pragma unroll
        for (int r = 0; r < 8; ++r) {
            const int idx = tid + r * 256;
            const int k = idx >> 5;
            const int j4 = idx & 31;
            *(float4*)&Ws[k][j4 * 4] =
                *(const float4*)&Wsrc[(size_t)(koff + k) * D + j4 * 4];
        }
        __syncthreads();
#pragma unroll 4
        for (int k = 0; k < 64; ++k) {
            const float a0 = As[ty4 + 0][k], a1 = As[ty4 + 1][k];
            const float a2 = As[ty4 + 2][k], a3 = As[ty4 + 3][k];
            const float4 w0 = *(const float4*)&Ws[k][tx * 4];
            const float4 w1 = *(const float4*)&Ws[k][64 + tx * 4];
            acc[0][0] += a0 * w0.x; acc[0][1] += a0 * w0.y; acc[0][2] += a0 * w0.z; acc[0][3] += a0 * w0.w;
            acc[0][4] += a0 * w1.x; acc[0][5] += a0 * w1.y; acc[0][6] += a0 * w1.z; acc[0][7] += a0 * w1.w;
            acc[1][0] += a1 * w0.x; acc[1][1] += a1 * w0.y; acc[1][2] += a1 * w0.z; acc[1][3] += a1 * w0.w;
            acc[1][4] += a1 * w1.x; acc[1][5] += a1 * w1.y; acc[1][6] += a1 * w1.z; acc[1][7] += a1 * w1.w;
            acc[2][0] += a2 * w0.x; acc[2][1] += a2 * w0.y; acc[2][2] += a2 * w0.z; acc[2][3] += a2 * w0.w;
            acc[2][4] += a2 * w1.x; acc[2][5] += a2 * w1.y; acc[2][6] += a2 * w1.z; acc[2][7] += a2 * w1.w;
            acc[3][0] += a3 * w0.x; acc[3][1] += a3 * w0.y; acc[3][2] += a3 * w0.z; acc[3][3] += a3 * w0.w;
            acc[3][4] += a3 * w1.x; acc[3][5] += a3 * w1.y; acc[3][6] += a3 * w1.z; acc[3][7] += a3 * w1.w;
        }
    }
    const float4 bv0 = *(const float4*)&b_l[tx * 4];
    const float4 bv1 = *(const float4*)&b_l[64 + tx * 4];
#pragma unroll
    for (int i = 0; i < 4; ++i) {
        const int m = m0 + ty4 + i;
        if (m < M) {
            float4 o0, o1;
            o0.x = acc[i][0] + bv0.x; o0.y = acc[i][1] + bv0.y;
            o0.z = acc[i][2] + bv0.z; o0.w = acc[i][3] + bv0.w;
            o1.x = acc[i][4] + bv1.x; o1.y = acc[i][5] + bv1.y;
            o1.z = acc[i][6] + bv1.z; o1.w = acc[i][7] + bv1.w;
            *(float4*)&out[(size_t)m * D + tx * 4] = o0;
            *(float4*)&out[(size_t)m * D + 64 + tx * 4] = o1;
        }
    }
}

static inline size_t align256(size_t x) { return (x + 255) & ~(size_t)255; }

extern "C" void kernel_launch(void* const* d_in, const int* in_sizes, int n_in,
                              void* d_out, int out_size, void* d_ws, size_t ws_size,
                              hipStream_t stream) {
    const float* x   = (const float*)d_in[0];
    const int*   row = (const int*)d_in[1];
    const int*   col = (const int*)d_in[2];
    const float* val = (const float*)d_in[3];
    const float* W_l = (const float*)d_in[4];
    const float* b_l = (const float*)d_in[5];
    const float* W_r = (const float*)d_in[6];
    float* out = (float*)d_out;

    const int n_nodes = in_sizes[0] / D;
    const int n_edges = in_sizes[1];

    const size_t xh_bytes   = (size_t)n_nodes * D * 2;
    const size_t outl_bytes = (size_t)n_nodes * D * 2;
    const size_t wt_bytes   = (size_t)D * D * 2;
    const size_t rp_bytes   = (size_t)(n_nodes + 1) * 4;
    size_t off = 0;
    const size_t xh_off   = off; off += align256(xh_bytes);
    const size_t outl_off = off; off += align256(outl_bytes);
    const size_t wlt_off  = off; off += align256(wt_bytes);
    const size_t wrt_off  = off; off += align256(wt_bytes);
    const size_t rp_off   = off; off += align256(rp_bytes);
    const size_t needed   = off + 65536;

    if (ws_size >= needed) {
        unsigned short* xh    = (unsigned short*)((char*)d_ws + xh_off);
        unsigned short* outlh = (unsigned short*)((char*)d_ws + outl_off);
        unsigned short* Wlt   = (unsigned short*)((char*)d_ws + wlt_off);
        unsigned short* Wrt   = (unsigned short*)((char*)d_ws + wrt_off);
        int* row_ptr          = (int*)((char*)d_ws + rp_off);

        const int n8 = n_nodes * D / 8;
        const int nbConv = (n8 + 255) / 256;
        const int nbRp   = (n_edges + 255) / 256;
        const int nbW    = 64;
        prep_kernel<<<nbConv + nbRp + nbW, 256, 0, stream>>>(
            x, xh, n8, row, row_ptr, n_nodes, n_edges,
            W_l, W_r, Wlt, Wrt, nbConv, nbRp);
        spmm_mfma_kernel<<<(n_nodes + BN - 1) / BN, 256, 0, stream>>>(
            xh, row_ptr, row, col, val, outlh, n_nodes);
        gemm_mfma_kernel<<<(n_nodes + 63) / 64, 256, 0, stream>>>(
            xh, outlh, Wlt, Wrt, b_l, out, n_nodes);
    } else {
        int* row_ptr = (int*)d_ws;
        build_rowptr_kernel<<<(n_edges + 255) / 256, 256, 0, stream>>>(
            row, row_ptr, n_nodes, n_edges);
        spmm_kernel<<<n_nodes, 128, 0, stream>>>(x, row_ptr, col, val, out);
        fused_gemm_kernel<<<(n_nodes + 63) / 64, 256, 0, stream>>>(
            x, W_l, b_l, W_r, out, n_nodes);
    }
}

// Round 10
// 108.863 us; speedup vs baseline: 1.2557x; 1.2557x over previous
//
#include <hip/hip_runtime.h>

#define D 128
#define EDGE_CAP 1024
typedef unsigned int uint32;
typedef __bf16 bf16x8 __attribute__((ext_vector_type(8)));
typedef float f32x4 __attribute__((ext_vector_type(4)));

__device__ __forceinline__ unsigned short f2bf(float f) {
    unsigned u = __float_as_uint(f);
    unsigned r = u + 0x7FFFu + ((u >> 16) & 1u);   // round-to-nearest-even
    return (unsigned short)(r >> 16);
}
__device__ __forceinline__ float bflo(uint32 u) { return __uint_as_float(u << 16); }
__device__ __forceinline__ float bfhi(uint32 u) { return __uint_as_float(u & 0xFFFF0000u); }

__device__ __forceinline__ void fma8(float* acc, uint4 r, float v) {
    acc[0] += v * bflo(r.x); acc[1] += v * bfhi(r.x);
    acc[2] += v * bflo(r.y); acc[3] += v * bfhi(r.y);
    acc[4] += v * bflo(r.z); acc[5] += v * bfhi(r.z);
    acc[6] += v * bflo(r.w); acc[7] += v * bfhi(r.w);
}

// ---------------------------------------------------------------------------
// Fused prep: x->bf16 | CSR row_ptr | W transpose+convert
// ---------------------------------------------------------------------------
__global__ __launch_bounds__(256) void prep_kernel(
    const float* __restrict__ x, unsigned short* __restrict__ xh, int n8,
    const int* __restrict__ row, int* __restrict__ row_ptr,
    int n_nodes, int n_edges,
    const float* __restrict__ Wl, const float* __restrict__ Wr,
    unsigned short* __restrict__ Wlt, unsigned short* __restrict__ Wrt,
    int nbConv, int nbRp) {
    const int b = blockIdx.x;
    if (b < nbConv) {
        const int id = b * 256 + threadIdx.x;
        if (id < n8) {
            const float4* p = (const float4*)x + (size_t)id * 2;
            float4 a = p[0], bb = p[1];
            uint4 o;
            o.x = f2bf(a.x) | ((uint32)f2bf(a.y) << 16);
            o.y = f2bf(a.z) | ((uint32)f2bf(a.w) << 16);
            o.z = f2bf(bb.x) | ((uint32)f2bf(bb.y) << 16);
            o.w = f2bf(bb.z) | ((uint32)f2bf(bb.w) << 16);
            ((uint4*)xh)[id] = o;
        }
    } else if (b < nbConv + nbRp) {
        const int e = (b - nbConv) * 256 + threadIdx.x;
        if (e < n_edges) {
            const int r = row[e];
            const int rp = (e == 0) ? -1 : row[e - 1];
            for (int n = rp + 1; n <= r; ++n) row_ptr[n] = e;
            if (e == n_edges - 1)
                for (int n = r + 1; n <= n_nodes; ++n) row_ptr[n] = n_edges;
        }
    } else {
        const int id = (b - nbConv - nbRp) * 256 + threadIdx.x;   // 0..16383
        if (id < 16384) {
            const int n = id & 127, k = id >> 7;
            Wlt[n * 128 + k] = f2bf(Wl[k * 128 + n]);
            Wrt[n * 128 + k] = f2bf(Wr[k * 128 + n]);
        }
    }
}

// ---------------------------------------------------------------------------
// FUSED SpMM + GEMM. Block = 256 thr = 4 waves = 16 nodes.
// Phase 1 (round-5 gather, proven 59.8us): (col,val) in LDS; 16-lane group
//   per node; software-pipelined quads of gathers; acc[8] f32 per lane.
// Phase 2: A-tile LDS [16][264]: cols 0..127 = out_l (bf16 from acc),
//   cols 128..255 = x rows (staged before phase 1, overlapped).
// Phase 3: out[16x128] = A @ [Wlt;Wrt]^T + b_l via 16 MFMAs/wave
//   (wave owns 32 cols), f32 epilogue straight to d_out.
// Kills the outlh roundtrip (51 MB) + separate GEMM launch.
// ---------------------------------------------------------------------------
__global__ __launch_bounds__(256) void spmm_gemm_kernel(
    const unsigned short* __restrict__ xh,
    const int* __restrict__ row_ptr,
    const int* __restrict__ col,
    const float* __restrict__ val,
    const unsigned short* __restrict__ Wlt,
    const unsigned short* __restrict__ Wrt,
    const float* __restrict__ b_l,
    float* __restrict__ out, int n_nodes) {
    __shared__ int2 scv[EDGE_CAP];                // 8 KB
    __shared__ unsigned short A_lds[16][264];     // 8.25 KB (pad 8 shorts)
    const int tid = threadIdx.x;
    const int n0 = blockIdx.x * 16;
    const int e0 = row_ptr[n0];
    const int e1 = row_ptr[min(n0 + 16, n_nodes)];
    const int ne = e1 - e0;
    const bool fits = (ne <= EDGE_CAP);
    if (fits) {
        for (int t = tid; t < ne; t += 256)
            scv[t] = make_int2(col[e0 + t], __float_as_int(val[e0 + t]));
    }

    // stage x half of A-tile early (overlaps the gather loop)
    {
        const int r = tid >> 4, ch = tid & 15;
        uint4 v = make_uint4(0u, 0u, 0u, 0u);
        if (n0 + r < n_nodes)
            v = *(const uint4*)&xh[(size_t)(n0 + r) * D + ch * 8];
        *(uint4*)&A_lds[r][128 + ch * 8] = v;
    }
    __syncthreads();

    const int wv = tid >> 6, lane = tid & 63;
    const int g = lane >> 4, lq = lane & 15;
    const int nloc = wv * 4 + g;
    const int n = n0 + nloc;

    int s = 0, e = 0;
    if (n < n_nodes) { s = row_ptr[n]; e = row_ptr[n + 1]; }

    float acc[8] = {0.f, 0.f, 0.f, 0.f, 0.f, 0.f, 0.f, 0.f};

    if (fits) {
        auto fetch = [&](int idx, int& c, float& v) {
            if (idx < e) {
                const int li = idx - e0;
                if (li < EDGE_CAP) { c = scv[li].x; v = __int_as_float(scv[li].y); }
                else               { c = col[idx]; v = val[idx]; }
            } else { c = 0; v = 0.f; }
        };

        int i = s;
        int c0, c1, c2, c3; float v0, v1, v2, v3;
        fetch(i + 0, c0, v0); fetch(i + 1, c1, v1);
        fetch(i + 2, c2, v2); fetch(i + 3, c3, v3);
        uint4 r0 = *(const uint4*)&xh[c0 * D + lq * 8];
        uint4 r1 = *(const uint4*)&xh[c1 * D + lq * 8];
        uint4 r2 = *(const uint4*)&xh[c2 * D + lq * 8];
        uint4 r3 = *(const uint4*)&xh[c3 * D + lq * 8];

        while (i < e) {
            const int i2 = i + 4;
            int d0, d1, d2, d3; float w0, w1, w2, w3;
            fetch(i2 + 0, d0, w0); fetch(i2 + 1, d1, w1);
            fetch(i2 + 2, d2, w2); fetch(i2 + 3, d3, w3);
            const uint4 t0 = *(const uint4*)&xh[d0 * D + lq * 8];
            const uint4 t1 = *(const uint4*)&xh[d1 * D + lq * 8];
            const uint4 t2 = *(const uint4*)&xh[d2 * D + lq * 8];
            const uint4 t3 = *(const uint4*)&xh[d3 * D + lq * 8];
            fma8(acc, r0, v0);
            fma8(acc, r1, v1);
            fma8(acc, r2, v2);
            fma8(acc, r3, v3);
            r0 = t0; r1 = t1; r2 = t2; r3 = t3;
            v0 = w0; v1 = w1; v2 = w2; v3 = w3;
            i = i2;
        }
    } else {
        for (int j = s; j < e; ++j) {
            const int c = col[j];
            const float v = val[j];
            const uint4 r = *(const uint4*)&xh[(size_t)c * D + lq * 8];
            fma8(acc, r, v);
        }
    }

    // ---- phase 2: out_l -> A_lds cols 0..127 (bf16) ----
    {
        uint4 o;
        o.x = f2bf(acc[0]) | ((uint32)f2bf(acc[1]) << 16);
        o.y = f2bf(acc[2]) | ((uint32)f2bf(acc[3]) << 16);
        o.z = f2bf(acc[4]) | ((uint32)f2bf(acc[5]) << 16);
        o.w = f2bf(acc[6]) | ((uint32)f2bf(acc[7]) << 16);
        *(uint4*)&A_lds[nloc][lq * 8] = o;
    }
    __syncthreads();

    // ---- phase 3: MFMA epilogue. Wave wv owns cols [wv*32, wv*32+32). ----
    const int fr = lane & 15;
    const int kofs = (lane >> 4) * 8;
    f32x4 acc2[2];
    acc2[0] = (f32x4){0.f, 0.f, 0.f, 0.f};
    acc2[1] = (f32x4){0.f, 0.f, 0.f, 0.f};
#pragma unroll
    for (int st = 0; st < 8; ++st) {
        const int k0 = st * 32;
        const unsigned short* Wsel = (k0 < 128) ? Wlt : Wrt;
        const int kk = k0 & 127;
        const bf16x8 a = *(const bf16x8*)&A_lds[fr][k0 + kofs];
#pragma unroll
        for (int nr = 0; nr < 2; ++nr) {
            const int ncol = wv * 32 + nr * 16 + fr;
            const bf16x8 b = *(const bf16x8*)&Wsel[ncol * 128 + kk + kofs];
            acc2[nr] = __builtin_amdgcn_mfma_f32_16x16x32_bf16(
                a, b, acc2[nr], 0, 0, 0);
        }
    }
    const int r0c = (lane >> 4) * 4;
#pragma unroll
    for (int nr = 0; nr < 2; ++nr) {
        const int ncol = wv * 32 + nr * 16 + fr;
        const float bias = b_l[ncol];
#pragma unroll
        for (int j = 0; j < 4; ++j) {
            const int m = n0 + r0c + j;
            if (m < n_nodes) out[(size_t)m * D + ncol] = acc2[nr][j] + bias;
        }
    }
}

// ===========================================================================
// Fallback f32 path if ws is too small for bf16 staging.
// ===========================================================================
__global__ void build_rowptr_kernel(const int* __restrict__ row,
                                    int* __restrict__ row_ptr,
                                    int n_nodes, int n_edges) {
    int e = blockIdx.x * blockDim.x + threadIdx.x;
    if (e >= n_edges) return;
    int r = row[e];
    int rp = (e == 0) ? -1 : row[e - 1];
    for (int n = rp + 1; n <= r; ++n) row_ptr[n] = e;
    if (e == n_edges - 1)
        for (int n = r + 1; n <= n_nodes; ++n) row_ptr[n] = n_edges;
}

__global__ __launch_bounds__(128) void spmm_kernel(
    const float* __restrict__ x, const int* __restrict__ row_ptr,
    const int* __restrict__ col, const float* __restrict__ val,
    float* __restrict__ out_l) {
    const int n = blockIdx.x;
    const int d = threadIdx.x;
    const int start = row_ptr[n];
    const int end = row_ptr[n + 1];
    float acc = 0.0f;
    for (int e = start; e < end; ++e)
        acc += val[e] * x[(size_t)col[e] * D + d];
    out_l[(size_t)n * D + d] = acc;
}

__global__ __launch_bounds__(256) void fused_gemm_kernel(
    const float* __restrict__ xin, const float* __restrict__ W_l,
    const float* __restrict__ b_l, const float* __restrict__ W_r,
    float* __restrict__ out, int M) {
    __shared__ float As[64][68];
    __shared__ float Ws[64][132];
    const int tid = threadIdx.x;
    const int tx = tid & 15;
    const int ty = tid >> 4;
    const int ty4 = ty * 4;
    const int m0 = blockIdx.x * 64;
    float acc[4][8];
#pragma unroll
    for (int i = 0; i < 4; ++i)
#pragma unroll
        for (int j = 0; j < 8; ++j) acc[i][j] = 0.0f;
    for (int kt = 0; kt < 4; ++kt) {
        const float* Asrc = (kt < 2) ? out : xin;
        const float* Wsrc = (kt < 2) ? W_l : W_r;
        const int koff = (kt & 1) * 64;
        __syncthreads();
#pragma unroll
        for (int r = 0; r < 4; ++r) {
            const int idx = tid + r * 256;
            const int m = idx >> 4;
            const int kq = idx & 15;
            float4 a = make_float4(0.f, 0.f, 0.f, 0.f);
            if (m0 + m < M)
                a = *(const float4*)&Asrc[(size_t)(m0 + m) * D + koff + kq * 4];
            *(float4*)&As[m][kq * 4] = a;
        }
#pragma unroll
        for (int r = 0; r < 8; ++r) {
            const int idx = tid + r * 256;
            const int k = idx >> 5;
            const int j4 = idx & 31;
            *(float4*)&Ws[k][j4 * 4] =
                *(const float4*)&Wsrc[(size_t)(koff + k) * D + j4 * 4];
        }
        __syncthreads();
#pragma unroll 4
        for (int k = 0; k < 64; ++k) {
            const float a0 = As[ty4 + 0][k], a1 = As[ty4 + 1][k];
            const float a2 = As[ty4 + 2][k], a3 = As[ty4 + 3][k];
            const float4 w0 = *(const float4*)&Ws[k][tx * 4];
            const float4 w1 = *(const float4*)&Ws[k][64 + tx * 4];
            acc[0][0] += a0 * w0.x; acc[0][1] += a0 * w0.y; acc[0][2] += a0 * w0.z; acc[0][3] += a0 * w0.w;
            acc[0][4] += a0 * w1.x; acc[0][5] += a0 * w1.y; acc[0][6] += a0 * w1.z; acc[0][7] += a0 * w1.w;
            acc[1][0] += a1 * w0.x; acc[1][1] += a1 * w0.y; acc[1][2] += a1 * w0.z; acc[1][3] += a1 * w0.w;
            acc[1][4] += a1 * w1.x; acc[1][5] += a1 * w1.y; acc[1][6] += a1 * w1.z; acc[1][7] += a1 * w1.w;
            acc[2][0] += a2 * w0.x; acc[2][1] += a2 * w0.y; acc[2][2] += a2 * w0.z; acc[2][3] += a2 * w0.w;
            acc[2][4] += a2 * w1.x; acc[2][5] += a2 * w1.y; acc[2][6] += a2 * w1.z; acc[2][7] += a2 * w1.w;
            acc[3][0] += a3 * w0.x; acc[3][1] += a3 * w0.y; acc[3][2] += a3 * w0.z; acc[3][3] += a3 * w0.w;
            acc[3][4] += a3 * w1.x; acc[3][5] += a3 * w1.y; acc[3][6] += a3 * w1.z; acc[3][7] += a3 * w1.w;
        }
    }
    const float4 bv0 = *(const float4*)&b_l[tx * 4];
    const float4 bv1 = *(const float4*)&b_l[64 + tx * 4];
#pragma unroll
    for (int i = 0; i < 4; ++i) {
        const int m = m0 + ty4 + i;
        if (m < M) {
            float4 o0, o1;
            o0.x = acc[i][0] + bv0.x; o0.y = acc[i][1] + bv0.y;
            o0.z = acc[i][2] + bv0.z; o0.w = acc[i][3] + bv0.w;
            o1.x = acc[i][4] + bv1.x; o1.y = acc[i][5] + bv1.y;
            o1.z = acc[i][6] + bv1.z; o1.w = acc[i][7] + bv1.w;
            *(float4*)&out[(size_t)m * D + tx * 4] = o0;
            *(float4*)&out[(size_t)m * D + 64 + tx * 4] = o1;
        }
    }
}

static inline size_t align256(size_t x) { return (x + 255) & ~(size_t)255; }

extern "C" void kernel_launch(void* const* d_in, const int* in_sizes, int n_in,
                              void* d_out, int out_size, void* d_ws, size_t ws_size,
                              hipStream_t stream) {
    const float* x   = (const float*)d_in[0];
    const int*   row = (const int*)d_in[1];
    const int*   col = (const int*)d_in[2];
    const float* val = (const float*)d_in[3];
    const float* W_l = (const float*)d_in[4];
    const float* b_l = (const float*)d_in[5];
    const float* W_r = (const float*)d_in[6];
    float* out = (float*)d_out;

    const int n_nodes = in_sizes[0] / D;
    const int n_edges = in_sizes[1];

    const size_t xh_bytes = (size_t)n_nodes * D * 2;
    const size_t wt_bytes = (size_t)D * D * 2;
    const size_t rp_bytes = (size_t)(n_nodes + 1) * 4;
    size_t off = 0;
    const size_t xh_off  = off; off += align256(xh_bytes);
    const size_t wlt_off = off; off += align256(wt_bytes);
    const size_t wrt_off = off; off += align256(wt_bytes);
    const size_t rp_off  = off; off += align256(rp_bytes);
    const size_t needed  = off + 65536;

    if (ws_size >= needed) {
        unsigned short* xh  = (unsigned short*)((char*)d_ws + xh_off);
        unsigned short* Wlt = (unsigned short*)((char*)d_ws + wlt_off);
        unsigned short* Wrt = (unsigned short*)((char*)d_ws + wrt_off);
        int* row_ptr        = (int*)((char*)d_ws + rp_off);

        const int n8 = n_nodes * D / 8;
        const int nbConv = (n8 + 255) / 256;
        const int nbRp   = (n_edges + 255) / 256;
        const int nbW    = 64;
        prep_kernel<<<nbConv + nbRp + nbW, 256, 0, stream>>>(
            x, xh, n8, row, row_ptr, n_nodes, n_edges,
            W_l, W_r, Wlt, Wrt, nbConv, nbRp);
        spmm_gemm_kernel<<<(n_nodes + 15) / 16, 256, 0, stream>>>(
            xh, row_ptr, col, val, Wlt, Wrt, b_l, out, n_nodes);
    } else {
        int* row_ptr = (int*)d_ws;
        build_rowptr_kernel<<<(n_edges + 255) / 256, 256, 0, stream>>>(
            row, row_ptr, n_nodes, n_edges);
        spmm_kernel<<<n_nodes, 128, 0, stream>>>(x, row_ptr, col, val, out);
        fused_gemm_kernel<<<(n_nodes + 63) / 64, 256, 0, stream>>>(
            x, W_l, b_l, W_r, out, n_nodes);
    }
}